// Round 14
// baseline (161.601 us; speedup 1.0000x reference)
//
#include <hip/hip_runtime.h>

#define NN 100000
#define NE 1600000
#define SB   391      // sort blocks (4096 edges each; 391*4096 >= NE)
#define NBKT 391      // buckets of 256 nodes (dst>>8)
#define EPB  4096     // edges per sort block

typedef _Float16 f16x8 __attribute__((ext_vector_type(8)));
typedef float    f32x4 __attribute__((ext_vector_type(4)));

// ===================== prep: zero aggr | pack h | pack w | sortA ==========
#define ZB   1563   // zero-aggr blocks
#define PHB  3125   // pack_h blocks (NN*8 threads)
#define PWB  13     // pack_w blocks (3328 threads)
// + SB sortA blocks appended

extern "C" __global__ void __launch_bounds__(256)
prep_kernel(const float* __restrict__ pos, const float* __restrict__ vel,
            const int* __restrict__ ei,
            const float* __restrict__ mw1, const float* __restrict__ mw2,
            const float* __restrict__ uw1, const float* __restrict__ uw2,
            const float* __restrict__ pw,
            _Float16* __restrict__ hh,
            _Float16* __restrict__ mw1f, _Float16* __restrict__ mw2f,
            _Float16* __restrict__ uw1f, _Float16* __restrict__ uw2f,
            _Float16* __restrict__ pwf,
            float* __restrict__ aggr, int* __restrict__ cntm)
{
    __shared__ int lh[NBKT];
    const int b = blockIdx.x, tid = threadIdx.x;
    if (b < ZB) {                                      // zero aggr (25.6 MB)
        float4* p = (float4*)aggr;
        const int base4 = b * 1024 + tid;
        const float4 z = make_float4(0.f, 0.f, 0.f, 0.f);
#pragma unroll
        for (int k = 0; k < 4; ++k) {
            const int idx = base4 + k * 256;
            if (idx < NN * 16) p[idx] = z;
        }
    } else if (b < ZB + PHB) {                         // pack h -> fp16
        const int t = (b - ZB) * 256 + tid;
        const int node = t >> 3, seg = t & 7;
        const float* src = (seg < 4) ? pos + (size_t)node * 32 + seg * 8
                                     : vel + (size_t)node * 32 + (seg - 4) * 8;
        const float4 a = ((const float4*)src)[0];
        const float4 c = ((const float4*)src)[1];
        f16x8 r;
        r[0]=(_Float16)a.x; r[1]=(_Float16)a.y; r[2]=(_Float16)a.z; r[3]=(_Float16)a.w;
        r[4]=(_Float16)c.x; r[5]=(_Float16)c.y; r[6]=(_Float16)c.z; r[7]=(_Float16)c.w;
        *(f16x8*)(hh + (size_t)node * 64 + seg * 8) = r;
    } else if (b < ZB + PHB + PWB) {                   // pack weights (16x16 frags)
        const int t2 = (b - ZB - PHB) * 256 + tid;
        if (t2 < 1024) {                               // msg_w1 [128,64]
            const int t = t2 >> 8, kk = (t2 >> 6) & 3, l = t2 & 63;
            f16x8 r;
#pragma unroll
            for (int j = 0; j < 8; ++j)
                r[j] = (_Float16)mw1[(kk * 32 + (l >> 4) * 8 + j) * 64 + t * 16 + (l & 15)];
            *(f16x8*)(mw1f + (size_t)t2 * 8) = r;
        } else if (t2 < 1536) {                        // msg_w2 [64,64]
            const int i = t2 - 1024;
            const int t = i >> 7, kk = (i >> 6) & 1, l = i & 63;
            f16x8 r;
#pragma unroll
            for (int j = 0; j < 8; ++j)
                r[j] = (_Float16)mw2[(kk * 32 + (l >> 4) * 8 + j) * 64 + t * 16 + (l & 15)];
            *(f16x8*)(mw2f + (size_t)i * 8) = r;
        } else if (t2 < 2560) {                        // upd_w1 [128,64]
            const int i = t2 - 1536;
            const int t = i >> 8, kk = (i >> 6) & 3, l = i & 63;
            f16x8 r;
#pragma unroll
            for (int j = 0; j < 8; ++j)
                r[j] = (_Float16)uw1[(kk * 32 + (l >> 4) * 8 + j) * 64 + t * 16 + (l & 15)];
            *(f16x8*)(uw1f + (size_t)i * 8) = r;
        } else if (t2 < 3072) {                        // upd_w2 [64,64]
            const int i = t2 - 2560;
            const int t = i >> 7, kk = (i >> 6) & 1, l = i & 63;
            f16x8 r;
#pragma unroll
            for (int j = 0; j < 8; ++j)
                r[j] = (_Float16)uw2[(kk * 32 + (l >> 4) * 8 + j) * 64 + t * 16 + (l & 15)];
            *(f16x8*)(uw2f + (size_t)i * 8) = r;
        } else if (t2 < 3328) {                        // pred_w [64,32]
            const int i = t2 - 3072;
            const int t = i >> 7, kk = (i >> 6) & 1, l = i & 63;
            f16x8 r;
#pragma unroll
            for (int j = 0; j < 8; ++j)
                r[j] = (_Float16)pw[(kk * 32 + (l >> 4) * 8 + j) * 32 + t * 16 + (l & 15)];
            *(f16x8*)(pwf + (size_t)i * 8) = r;
        }
    } else {                                           // sortA: LDS bucket hist
        const int blk = b - (ZB + PHB + PWB);
        for (int i = tid; i < NBKT; i += 256) lh[i] = 0;
        __syncthreads();
        const int e0 = blk * EPB;
#pragma unroll
        for (int k = 0; k < EPB / 256; ++k) {
            const int e = e0 + k * 256 + tid;
            if (e < NE) atomicAdd(&lh[ei[NE + e] >> 8], 1);
        }
        __syncthreads();
        for (int i = tid; i < NBKT; i += 256) cntm[blk * NBKT + i] = lh[i];
    }
}

// ===================== scancol: column scan + atomic bucket base ==========
extern "C" __global__ void __launch_bounds__(512)
scancol_kernel(const int* __restrict__ cntm, int* __restrict__ gtot,
               int* __restrict__ offs, int* __restrict__ btot,
               int* __restrict__ bbase)
{
    __shared__ int s[512];
    const int tid = threadIdx.x, bkt = blockIdx.x;
    const int v = (tid < SB) ? cntm[tid * NBKT + bkt] : 0;
    s[tid] = v;
    __syncthreads();
    for (int off = 1; off < 512; off <<= 1) {
        int t = (tid >= off) ? s[tid - off] : 0;
        __syncthreads();
        s[tid] += t;
        __syncthreads();
    }
    if (tid < SB) offs[tid * NBKT + bkt] = s[tid] - v;   // exclusive in column
    if (tid == SB - 1) {
        const int tot = s[tid];
        btot[bkt]  = tot;
        bbase[bkt] = atomicAdd(gtot, tot);   // disjoint range; order arbitrary
    }
}

// ===================== sortC: scatter edges into bucket-grouped order =====
extern "C" __global__ void __launch_bounds__(256)
sortC_kernel(const int* __restrict__ ei, const int* __restrict__ offs,
             const int* __restrict__ bbase, int2* __restrict__ sd_tmp)
{
    __shared__ int lh[NBKT];
    __shared__ int lo[NBKT];
    const int tid = threadIdx.x, blk = blockIdx.x;
    for (int i = tid; i < NBKT; i += 256) {
        lh[i] = 0;
        lo[i] = bbase[i] + offs[blk * NBKT + i];
    }
    __syncthreads();
    const int e0 = blk * EPB;
#pragma unroll
    for (int k = 0; k < EPB / 256; ++k) {
        const int e = e0 + k * 256 + tid;
        if (e < NE) {
            const int s = ei[e], d = ei[NE + e];
            const int bkt = d >> 8;
            const int r = atomicAdd(&lh[bkt], 1);
            sd_tmp[lo[bkt] + r] = make_int2(s, d);
        }
    }
}

// ===================== sortD: within-bucket dst sort ======================
extern "C" __global__ void __launch_bounds__(256)
sortD_kernel(const int2* __restrict__ sd_tmp, const int* __restrict__ bbase,
             const int* __restrict__ btot, int2* __restrict__ sd2)
{
    __shared__ int h[256];
    __shared__ int s[256];
    __shared__ int dbase[256];
    const int tid = threadIdx.x, bkt = blockIdx.x;
    const int s0 = bbase[bkt];
    const int n  = btot[bkt];
    h[tid] = 0;
    __syncthreads();
    for (int k = tid; k < n; k += 256)
        atomicAdd(&h[sd_tmp[s0 + k].y & 255], 1);
    __syncthreads();
    const int v = h[tid];
    s[tid] = v;
    __syncthreads();
    for (int off = 1; off < 256; off <<= 1) {
        int t = (tid >= off) ? s[tid - off] : 0;
        __syncthreads();
        s[tid] += t;
        __syncthreads();
    }
    dbase[tid] = s[tid] - v;
    __syncthreads();
    h[tid] = 0;           // reuse as running rank
    __syncthreads();
    for (int k = tid; k < n; k += 256) {
        const int2 e = sd_tmp[s0 + k];
        const int dl = e.y & 255;
        const int r = atomicAdd(&h[dl], 1);
        sd2[s0 + dbase[dl] + r] = e;
    }
}

// ===================== fused edge MLP + register segmented aggregation ====
// Block = 8 waves (512 thr); wave owns 64 dst-sorted slots (4 tiles of 16).
// r11 body (XOR-swizzled Y, 0 conflicts, lgkm drains) + 3-deep gather
// prefetch (~940cy hiding window >= HBM-miss) + setprio around MFMA (T5:
// independent phase-staggered waves) + bias in MFMA C-init.
// LDS = 24KB weights + 8x2KB = 40KB -> 4 blocks/CU.
extern "C" __global__ void __launch_bounds__(512, 4)
edgeagg_kernel(const _Float16* __restrict__ hh,
               const int2* __restrict__ sd,
               const _Float16* __restrict__ w1f, const _Float16* __restrict__ w2f,
               const float* __restrict__ b1, const float* __restrict__ b2,
               float* __restrict__ aggr)
{
    __shared__ _Float16 sW1[4 * 4 * 64 * 8];   // 16 KB
    __shared__ _Float16 sW2[4 * 2 * 64 * 8];   // 8 KB
    __shared__ _Float16 sT[8][16 * 64];        // 16 KB (wave-private Y)

    const int tid = threadIdx.x;
    const int wave = tid >> 6, lane = tid & 63;
    const int m = lane & 15, g = lane >> 4;
    const int wslot = (blockIdx.x * 8 + wave) * 64;

    const int2 sdv = sd[wslot + lane];
    const int prevd = __shfl_up(sdv.y, 1, 64);
    const unsigned long long bmask = __ballot(lane == 0 || sdv.y != prevd);

    {   // stage W fragments (24 KB, 512 threads)
        const uint4* g1 = (const uint4*)w1f; uint4* s1 = (uint4*)sW1;
        s1[tid] = g1[tid]; s1[512 + tid] = g1[512 + tid];
        const uint4* g2 = (const uint4*)w2f; uint4* s2 = (uint4*)sW2;
        s2[tid] = g2[tid];
    }

    const float bb1[4] = { b1[m], b1[16 + m], b1[32 + m], b1[48 + m] };
    const float bb2[4] = { b2[m], b2[16 + m], b2[32 + m], b2[48 + m] };

    __syncthreads();   // the only block barrier

    _Float16* Y = sT[wave];

    float racc = 0.0f;
    int   rnode = __builtin_amdgcn_readlane(sdv.y, 0);
    int   firstRun = 1;

    // 3-deep A-fragment pipeline: tiles 0 and 1 issued up front
    f16x8 Abuf[3][4];
#pragma unroll
    for (int p = 0; p < 2; ++p) {
        const int ns = __shfl(sdv.x, p * 16 + m, 64);
        const int nd = __shfl(sdv.y, p * 16 + m, 64);
        const _Float16* hd = hh + (size_t)nd * 64 + g * 8;
        const _Float16* hs = hh + (size_t)ns * 64 + g * 8;
        Abuf[p][0] = *(const f16x8*)(hd);
        Abuf[p][1] = *(const f16x8*)(hd + 32);
        Abuf[p][2] = *(const f16x8*)(hs);
        Abuf[p][3] = *(const f16x8*)(hs + 32);
    }

#pragma unroll
    for (int it = 0; it < 4; ++it) {
        const int cur = it % 3;
        if (it < 2) {   // issue tile it+2's gathers (2 tiles ahead)
            const int nxt = (it + 2) % 3;
            const int ns = __shfl(sdv.x, (it + 2) * 16 + m, 64);
            const int nd = __shfl(sdv.y, (it + 2) * 16 + m, 64);
            const _Float16* hd = hh + (size_t)nd * 64 + g * 8;
            const _Float16* hs = hh + (size_t)ns * 64 + g * 8;
            Abuf[nxt][0] = *(const f16x8*)(hd);
            Abuf[nxt][1] = *(const f16x8*)(hd + 32);
            Abuf[nxt][2] = *(const f16x8*)(hs);
            Abuf[nxt][3] = *(const f16x8*)(hs + 32);
        }

        // ---- layer 1: 16 MFMAs, bias pre-loaded in accumulator
        f32x4 acc[4];
#pragma unroll
        for (int t = 0; t < 4; ++t) {
            acc[t][0] = bb1[t]; acc[t][1] = bb1[t];
            acc[t][2] = bb1[t]; acc[t][3] = bb1[t];
        }
        __builtin_amdgcn_s_setprio(1);
#pragma unroll
        for (int t = 0; t < 4; ++t) {
#pragma unroll
            for (int kk = 0; kk < 4; ++kk) {
                const f16x8 b = *(const f16x8*)(sW1 + ((t * 4 + kk) * 64 + lane) * 8);
                acc[t] = __builtin_amdgcn_mfma_f32_16x16x32_f16(Abuf[cur][kk], b, acc[t], 0, 0, 0);
            }
        }
        __builtin_amdgcn_s_setprio(0);

        // ---- relu -> fp16 -> swizzled wave-private Y tile
#pragma unroll
        for (int t = 0; t < 4; ++t) {
#pragma unroll
            for (int r = 0; r < 4; ++r) {
                const float y = fmaxf(acc[t][r], 0.0f);
                const int row = g * 4 + r, col = t * 16 + m;
                const int byteoff = row * 128 + ((2 * col) ^ ((row & 7) << 4));
                *(_Float16*)((char*)Y + byteoff) = (_Float16)y;
            }
        }
        asm volatile("s_waitcnt lgkmcnt(0)" ::: "memory");
        __builtin_amdgcn_sched_barrier(0);

        // ---- layer 2 A-frags from swizzled Y
        f16x8 a2[2];
#pragma unroll
        for (int kk = 0; kk < 2; ++kk) {
            const int c = kk * 4 + g;
            a2[kk] = *(const f16x8*)((char*)Y + m * 128 + ((c * 16) ^ ((m & 7) << 4)));
        }
        asm volatile("s_waitcnt lgkmcnt(0)" ::: "memory");
        __builtin_amdgcn_sched_barrier(0);

        // ---- layer 2: 8 MFMAs, bias pre-loaded
        f32x4 acc2[4];
#pragma unroll
        for (int t = 0; t < 4; ++t) {
            acc2[t][0] = bb2[t]; acc2[t][1] = bb2[t];
            acc2[t][2] = bb2[t]; acc2[t][3] = bb2[t];
        }
        __builtin_amdgcn_s_setprio(1);
#pragma unroll
        for (int kk = 0; kk < 2; ++kk) {
#pragma unroll
            for (int t = 0; t < 4; ++t) {
                const f16x8 b = *(const f16x8*)(sW2 + ((t * 2 + kk) * 64 + lane) * 8);
                acc2[t] = __builtin_amdgcn_mfma_f32_16x16x32_f16(a2[kk], b, acc2[t], 0, 0, 0);
            }
        }
        __builtin_amdgcn_s_setprio(0);

        // ---- register segmented reduction over dst runs in this tile
        const unsigned tm = (unsigned)((bmask >> (it * 16)) & 0xFFFFull) | 0x10000u;
        if (tm == 0x10000u) {
            // fast path: whole tile continues the current run
            float p0 = 0.f, p1 = 0.f, p2 = 0.f, p3 = 0.f;
#pragma unroll
            for (int r = 0; r < 4; ++r) {
                p0 += acc2[0][r]; p1 += acc2[1][r];
                p2 += acc2[2][r]; p3 += acc2[3][r];
            }
            p0 += __shfl_xor(p0, 16); p0 += __shfl_xor(p0, 32);
            p1 += __shfl_xor(p1, 16); p1 += __shfl_xor(p1, 32);
            p2 += __shfl_xor(p2, 16); p2 += __shfl_xor(p2, 32);
            p3 += __shfl_xor(p3, 16); p3 += __shfl_xor(p3, 32);
            racc += (g == 0) ? p0 : (g == 1) ? p1 : (g == 2) ? p2 : p3;
        } else {
            int a = 0;
            while (a < 16) {
                const int b = a + 1 + __builtin_ctz(tm >> (a + 1));   // segment [a,b)
                const int d = __builtin_amdgcn_readlane(sdv.y, it * 16 + a);
                if (d != rnode) {
                    float* ap = aggr + (size_t)rnode * 64 + lane;
                    if (firstRun) atomicAdd(ap, racc);
                    else          *ap = racc;
                    firstRun = 0; racc = 0.0f; rnode = d;
                }
                float p0 = 0.f, p1 = 0.f, p2 = 0.f, p3 = 0.f;
#pragma unroll
                for (int r = 0; r < 4; ++r) {
                    const int rowl = 4 * g + r;
                    const bool in = (rowl >= a) && (rowl < b);
                    p0 += in ? acc2[0][r] : 0.f;
                    p1 += in ? acc2[1][r] : 0.f;
                    p2 += in ? acc2[2][r] : 0.f;
                    p3 += in ? acc2[3][r] : 0.f;
                }
                p0 += __shfl_xor(p0, 16); p0 += __shfl_xor(p0, 32);
                p1 += __shfl_xor(p1, 16); p1 += __shfl_xor(p1, 32);
                p2 += __shfl_xor(p2, 16); p2 += __shfl_xor(p2, 32);
                p3 += __shfl_xor(p3, 16); p3 += __shfl_xor(p3, 32);
                racc += (g == 0) ? p0 : (g == 1) ? p1 : (g == 2) ? p2 : p3;
                a = b;
            }
        }
    }
    atomicAdd(aggr + (size_t)rnode * 64 + lane, racc);
}

// ===================== MFMA node kernel: h + fp32 aggr -> upd -> pred =====
extern "C" __global__ void __launch_bounds__(256)
node_mfma_kernel(const _Float16* __restrict__ hh, const float* __restrict__ aggr,
                 const _Float16* __restrict__ uw1f, const _Float16* __restrict__ uw2f,
                 const _Float16* __restrict__ pwf,
                 const float* __restrict__ b1, const float* __restrict__ b2,
                 const float* __restrict__ pb, float* __restrict__ out)
{
    __shared__ _Float16 sU1[4 * 4 * 64 * 8];   // 16 KB
    __shared__ _Float16 sU2[4 * 2 * 64 * 8];   // 8 KB
    __shared__ _Float16 sPW[2 * 2 * 64 * 8];   // 4 KB
    __shared__ _Float16 sT[4][16 * 64];        // 8 KB

    const int tid = threadIdx.x;
    {
        const uint4* g1 = (const uint4*)uw1f; uint4* s1 = (uint4*)sU1;
#pragma unroll
        for (int i = 0; i < 4; ++i) s1[i * 256 + tid] = g1[i * 256 + tid];
        const uint4* g2 = (const uint4*)uw2f; uint4* s2 = (uint4*)sU2;
#pragma unroll
        for (int i = 0; i < 2; ++i) s2[i * 256 + tid] = g2[i * 256 + tid];
        const uint4* g3 = (const uint4*)pwf;  uint4* s3 = (uint4*)sPW;
        s3[tid] = g3[tid];
    }
    __syncthreads();

    const int wave = tid >> 6, lane = tid & 63;
    const int m = lane & 15, g = lane >> 4;
    const int nb = (blockIdx.x * 4 + wave) * 16;
    const int v = nb + m;
    const int vl = (v < NN) ? v : (NN - 1);

    const _Float16* hv = hh + (size_t)vl * 64 + g * 8;
    const f16x8 a0 = *(const f16x8*)(hv);
    const f16x8 a1 = *(const f16x8*)(hv + 32);
    const float* av = aggr + (size_t)vl * 64 + g * 8;
    const float4 x0 = *(const float4*)(av),      x1 = *(const float4*)(av + 4);
    const float4 y0 = *(const float4*)(av + 32), y1 = *(const float4*)(av + 36);
    f16x8 a2, a3;
    a2[0]=(_Float16)x0.x; a2[1]=(_Float16)x0.y; a2[2]=(_Float16)x0.z; a2[3]=(_Float16)x0.w;
    a2[4]=(_Float16)x1.x; a2[5]=(_Float16)x1.y; a2[6]=(_Float16)x1.z; a2[7]=(_Float16)x1.w;
    a3[0]=(_Float16)y0.x; a3[1]=(_Float16)y0.y; a3[2]=(_Float16)y0.z; a3[3]=(_Float16)y0.w;
    a3[4]=(_Float16)y1.x; a3[5]=(_Float16)y1.y; a3[6]=(_Float16)y1.z; a3[7]=(_Float16)y1.w;

    // layer 1
    f32x4 acc[4] = {};
#pragma unroll
    for (int t = 0; t < 4; ++t) {
        acc[t] = __builtin_amdgcn_mfma_f32_16x16x32_f16(
            a0, *(const f16x8*)(sU1 + ((t * 4 + 0) * 64 + lane) * 8), acc[t], 0, 0, 0);
        acc[t] = __builtin_amdgcn_mfma_f32_16x16x32_f16(
            a1, *(const f16x8*)(sU1 + ((t * 4 + 1) * 64 + lane) * 8), acc[t], 0, 0, 0);
        acc[t] = __builtin_amdgcn_mfma_f32_16x16x32_f16(
            a2, *(const f16x8*)(sU1 + ((t * 4 + 2) * 64 + lane) * 8), acc[t], 0, 0, 0);
        acc[t] = __builtin_amdgcn_mfma_f32_16x16x32_f16(
            a3, *(const f16x8*)(sU1 + ((t * 4 + 3) * 64 + lane) * 8), acc[t], 0, 0, 0);
    }

    _Float16* Y = sT[wave];
#pragma unroll
    for (int t = 0; t < 4; ++t) {
        const float bb = b1[t * 16 + m];
#pragma unroll
        for (int r = 0; r < 4; ++r) {
            const float y = fmaxf(acc[t][r] + bb, 0.0f);
            const int row = g * 4 + r, col = t * 16 + m;
            const int byteoff = row * 128 + ((2 * col) ^ ((row & 7) << 4));
            *(_Float16*)((char*)Y + byteoff) = (_Float16)y;
        }
    }
    asm volatile("s_waitcnt lgkmcnt(0)" ::: "memory");
    __builtin_amdgcn_sched_barrier(0);

    f16x8 ay[2];
#pragma unroll
    for (int kk = 0; kk < 2; ++kk) {
        const int c = kk * 4 + g;
        ay[kk] = *(const f16x8*)((char*)Y + m * 128 + ((c * 16) ^ ((m & 7) << 4)));
    }
    asm volatile("s_waitcnt lgkmcnt(0)" ::: "memory");
    __builtin_amdgcn_sched_barrier(0);

    // layer 2
    f32x4 acc2[4] = {};
#pragma unroll
    for (int kk = 0; kk < 2; ++kk) {
#pragma unroll
        for (int t = 0; t < 4; ++t) {
            const f16x8 b = *(const f16x8*)(sU2 + ((t * 2 + kk) * 64 + lane) * 8);
            acc2[t] = __builtin_amdgcn_mfma_f32_16x16x32_f16(ay[kk], b, acc2[t], 0, 0, 0);
        }
    }

#pragma unroll
    for (int t = 0; t < 4; ++t) {
        const float bb = b2[t * 16 + m];
#pragma unroll
        for (int r = 0; r < 4; ++r) {
            const float u = acc2[t][r] + bb;
            const int row = g * 4 + r, col = t * 16 + m;
            const int byteoff = row * 128 + ((2 * col) ^ ((row & 7) << 4));
            *(_Float16*)((char*)Y + byteoff) = (_Float16)u;
        }
    }
    asm volatile("s_waitcnt lgkmcnt(0)" ::: "memory");
    __builtin_amdgcn_sched_barrier(0);

    f16x8 au[2];
#pragma unroll
    for (int kk = 0; kk < 2; ++kk) {
        const int c = kk * 4 + g;
        au[kk] = *(const f16x8*)((char*)Y + m * 128 + ((c * 16) ^ ((m & 7) << 4)));
    }
    asm volatile("s_waitcnt lgkmcnt(0)" ::: "memory");
    __builtin_amdgcn_sched_barrier(0);

    // pred head: 64 -> 32
    f32x4 acc3[2] = {};
#pragma unroll
    for (int kk = 0; kk < 2; ++kk) {
#pragma unroll
        for (int t = 0; t < 2; ++t) {
            const f16x8 b = *(const f16x8*)(sPW + ((t * 2 + kk) * 64 + lane) * 8);
            acc3[t] = __builtin_amdgcn_mfma_f32_16x16x32_f16(au[kk], b, acc3[t], 0, 0, 0);
        }
    }

    float* F = (float*)Y;
#pragma unroll
    for (int t = 0; t < 2; ++t) {
        const float bb = pb[t * 16 + m];
#pragma unroll
        for (int r = 0; r < 4; ++r) {
            const int row = g * 4 + r, col = t * 16 + m;
            const int byteoff = row * 128 + ((4 * col) ^ ((row & 7) << 4));
            *(float*)((char*)F + byteoff) = acc3[t][r] + bb;
        }
    }
    asm volatile("s_waitcnt lgkmcnt(0)" ::: "memory");
    __builtin_amdgcn_sched_barrier(0);

    const int row = lane >> 2, q = lane & 3;
    const float4 o0 = *(const float4*)((char*)F + row * 128 + ((q * 16)       ^ ((row & 7) << 4)));
    const float4 o1 = *(const float4*)((char*)F + row * 128 + (((q + 4) * 16) ^ ((row & 7) << 4)));
    if (nb + row < NN) {
        float4* op = (float4*)(out + (size_t)(nb + row) * 32);
        op[q]     = o0;
        op[q + 4] = o1;
    }
}

// ===================== fallback: atomic edge kernel + scalar node =========
extern "C" __global__ void __launch_bounds__(256)
edge_msg_kernel(const float* __restrict__ pos, const float* __restrict__ vel,
                const int* __restrict__ ei,
                const float* __restrict__ w1, const float* __restrict__ b1,
                const float* __restrict__ w2, const float* __restrict__ b2,
                float* __restrict__ aggr)
{
    const int e = blockIdx.x * 256 + threadIdx.x;
    if (e >= NE) return;
    const int ns = ei[e];
    const int nd = ei[NE + e];
    float y[64];
#pragma unroll
    for (int j = 0; j < 64; ++j) y[j] = b1[j];
    for (int part = 0; part < 4; ++part) {
        const int    node  = (part < 2) ? nd : ns;
        const float* basep = (part & 1) ? vel : pos;
        const float4* xp = reinterpret_cast<const float4*>(basep + (size_t)node * 32);
        const float*  wp = w1 + part * 32 * 64;
        for (int q = 0; q < 8; ++q) {
            const float4 xv = xp[q];
#pragma unroll
            for (int kk = 0; kk < 4; ++kk) {
                const float xs = (kk == 0) ? xv.x : (kk == 1) ? xv.y
                               : (kk == 2) ? xv.z : xv.w;
                const float* wr = wp + (q * 4 + kk) * 64;
#pragma unroll
                for (int j = 0; j < 64; ++j) y[j] = fmaf(xs, wr[j], y[j]);
            }
        }
    }
    float mm[64];
#pragma unroll
    for (int c = 0; c < 64; ++c) mm[c] = b2[c];
#pragma unroll
    for (int j = 0; j < 64; ++j) {
        const float yj = fmaxf(y[j], 0.0f);
        const float* wr = w2 + j * 64;
#pragma unroll
        for (int c = 0; c < 64; ++c) mm[c] = fmaf(yj, wr[c], mm[c]);
    }
    float* ap = aggr + (size_t)nd * 64;
#pragma unroll
    for (int c = 0; c < 64; ++c) atomicAdd(ap + c, mm[c]);
}

extern "C" __global__ void __launch_bounds__(256)
node_upd_kernel(const float* __restrict__ pos, const float* __restrict__ vel,
                const float* __restrict__ aggr,
                const float* __restrict__ w1, const float* __restrict__ b1,
                const float* __restrict__ w2, const float* __restrict__ b2,
                const float* __restrict__ pw, const float* __restrict__ pb,
                float* __restrict__ out)
{
    const int v = blockIdx.x * 256 + threadIdx.x;
    if (v >= NN) return;

    float y[64];
#pragma unroll
    for (int j = 0; j < 64; ++j) y[j] = b1[j];
    for (int part = 0; part < 4; ++part) {
        const float* basep = (part == 0) ? pos + (size_t)v * 32
                           : (part == 1) ? vel + (size_t)v * 32
                           : aggr + (size_t)v * 64 + (size_t)(part - 2) * 32;
        const float4* xp = reinterpret_cast<const float4*>(basep);
        const float*  wp = w1 + part * 32 * 64;
        for (int q = 0; q < 8; ++q) {
            const float4 xv = xp[q];
#pragma unroll
            for (int kk = 0; kk < 4; ++kk) {
                const float xs = (kk == 0) ? xv.x : (kk == 1) ? xv.y
                               : (kk == 2) ? xv.z : xv.w;
                const float* wr = wp + (q * 4 + kk) * 64;
#pragma unroll
                for (int j = 0; j < 64; ++j) y[j] = fmaf(xs, wr[j], y[j]);
            }
        }
    }

    float u[64];
#pragma unroll
    for (int c = 0; c < 64; ++c) u[c] = b2[c];
#pragma unroll
    for (int j = 0; j < 64; ++j) {
        const float yj = fmaxf(y[j], 0.0f);
        const float* wr = w2 + j * 64;
#pragma unroll
        for (int c = 0; c < 64; ++c) u[c] = fmaf(yj, wr[c], u[c]);
    }

    float o[32];
#pragma unroll
    for (int c = 0; c < 32; ++c) o[c] = pb[c];
#pragma unroll
    for (int j = 0; j < 64; ++j) {
        const float* wr = pw + j * 32;
#pragma unroll
        for (int c = 0; c < 32; ++c) o[c] = fmaf(u[j], wr[c], o[c]);
    }

    float4* op = reinterpret_cast<float4*>(out + (size_t)v * 32);
#pragma unroll
    for (int q = 0; q < 8; ++q)
        op[q] = make_float4(o[q * 4], o[q * 4 + 1], o[q * 4 + 2], o[q * 4 + 3]);
}

// ===================== launcher ===========================================
extern "C" void kernel_launch(void* const* d_in, const int* in_sizes, int n_in,
                              void* d_out, int out_size, void* d_ws, size_t ws_size,
                              hipStream_t stream)
{
    const float* pos = (const float*)d_in[0];
    const float* vel = (const float*)d_in[1];
    const int*   ei  = (const int*)d_in[2];
    const float* mw1 = (const float*)d_in[3];
    const float* mb1 = (const float*)d_in[4];
    const float* mw2 = (const float*)d_in[5];
    const float* mb2 = (const float*)d_in[6];
    const float* uw1 = (const float*)d_in[7];
    const float* ub1 = (const float*)d_in[8];
    const float* uw2 = (const float*)d_in[9];
    const float* ub2 = (const float*)d_in[10];
    const float* pw  = (const float*)d_in[11];
    const float* pb  = (const float*)d_in[12];
    float* out = (float*)d_out;

    // workspace layout (~66 MB total)
    char* ws = (char*)d_ws;
    size_t off = 0;
    float*    aggr   = (float*)(ws + off);    off += (size_t)NN * 64 * 4;     // 25.6 MB
    _Float16* hh     = (_Float16*)(ws + off); off += (size_t)NN * 64 * 2;     // 12.8 MB
    int2*     sd_tmp = (int2*)(ws + off);     off += (size_t)NE * 8;          // 12.8 MB
    int2*     sd2    = (int2*)(ws + off);     off += (size_t)NE * 8;          // 12.8 MB
    int*      cntm   = (int*)(ws + off);      off += (size_t)SB * NBKT * 4;   // 611 KB
    int*      offs   = (int*)(ws + off);      off += (size_t)SB * NBKT * 4;   // 611 KB
    int*      btot   = (int*)(ws + off);      off += 512 * 4;
    int*      bbase  = (int*)(ws + off);      off += 512 * 4;
    int*      gtot   = (int*)(ws + off);      off += 256;
    _Float16* mw1f   = (_Float16*)(ws + off); off += 1024 * 8 * 2;            // 16 KB
    _Float16* mw2f   = (_Float16*)(ws + off); off += 512 * 8 * 2;             // 8 KB
    _Float16* uw1f   = (_Float16*)(ws + off); off += 1024 * 8 * 2;            // 16 KB
    _Float16* uw2f   = (_Float16*)(ws + off); off += 512 * 8 * 2;             // 8 KB
    _Float16* pwf    = (_Float16*)(ws + off); off += 256 * 8 * 2;             // 4 KB
    const size_t need_full = off;

    if (ws_size >= need_full) {
        hipMemsetAsync(gtot, 0, sizeof(int), stream);
        prep_kernel<<<ZB + PHB + PWB + SB, 256, 0, stream>>>(
            pos, vel, ei, mw1, mw2, uw1, uw2, pw,
            hh, mw1f, mw2f, uw1f, uw2f, pwf, aggr, cntm);
        scancol_kernel<<<NBKT, 512, 0, stream>>>(cntm, gtot, offs, btot, bbase);
        sortC_kernel<<<SB, 256, 0, stream>>>(ei, offs, bbase, sd_tmp);
        sortD_kernel<<<NBKT, 256, 0, stream>>>(sd_tmp, bbase, btot, sd2);
        edgeagg_kernel<<<NE / 512, 512, 0, stream>>>(
            hh, sd2, mw1f, mw2f, mb1, mb2, aggr);
        node_mfma_kernel<<<(NN + 63) / 64, 256, 0, stream>>>(
            hh, aggr, uw1f, uw2f, pwf, ub1, ub2, pb, out);
    } else {
        // fallback: atomic path (needs only 25.6 MB)
        float* aggr2 = (float*)d_ws;
        hipMemsetAsync(aggr2, 0, (size_t)NN * 64 * sizeof(float), stream);
        edge_msg_kernel<<<NE / 256, 256, 0, stream>>>(pos, vel, ei,
                                                      mw1, mb1, mw2, mb2, aggr2);
        node_upd_kernel<<<(NN + 255) / 256, 256, 0, stream>>>(
            pos, vel, aggr2, uw1, ub1, uw2, ub2, pw, pb, out);
    }
}

// Round 15
// 137.005 us; speedup vs baseline: 1.1795x; 1.1795x over previous
//
#include <hip/hip_runtime.h>

#define NN 100000
#define NE 1600000
#define SB   391      // sort blocks (4096 edges each; 391*4096 >= NE)
#define NBKT 391      // buckets of 256 nodes (dst>>8)
#define EPB  4096     // edges per sort block

typedef _Float16 f16x8 __attribute__((ext_vector_type(8)));
typedef float    f32x4 __attribute__((ext_vector_type(4)));

// ===================== prep: zero aggr | pack h | pack w | sortA ==========
#define ZB   1563   // zero-aggr blocks
#define PHB  3125   // pack_h blocks (NN*8 threads)
#define PWB  13     // pack_w blocks (3328 threads)
// + SB sortA blocks appended

extern "C" __global__ void __launch_bounds__(256)
prep_kernel(const float* __restrict__ pos, const float* __restrict__ vel,
            const int* __restrict__ ei,
            const float* __restrict__ mw1, const float* __restrict__ mw2,
            const float* __restrict__ uw1, const float* __restrict__ uw2,
            const float* __restrict__ pw,
            _Float16* __restrict__ hh,
            _Float16* __restrict__ mw1f, _Float16* __restrict__ mw2f,
            _Float16* __restrict__ uw1f, _Float16* __restrict__ uw2f,
            _Float16* __restrict__ pwf,
            float* __restrict__ aggr, int* __restrict__ cntm)
{
    __shared__ int lh[NBKT];
    const int b = blockIdx.x, tid = threadIdx.x;
    if (b < ZB) {                                      // zero aggr (25.6 MB)
        float4* p = (float4*)aggr;
        const int base4 = b * 1024 + tid;
        const float4 z = make_float4(0.f, 0.f, 0.f, 0.f);
#pragma unroll
        for (int k = 0; k < 4; ++k) {
            const int idx = base4 + k * 256;
            if (idx < NN * 16) p[idx] = z;
        }
    } else if (b < ZB + PHB) {                         // pack h -> fp16
        const int t = (b - ZB) * 256 + tid;
        const int node = t >> 3, seg = t & 7;
        const float* src = (seg < 4) ? pos + (size_t)node * 32 + seg * 8
                                     : vel + (size_t)node * 32 + (seg - 4) * 8;
        const float4 a = ((const float4*)src)[0];
        const float4 c = ((const float4*)src)[1];
        f16x8 r;
        r[0]=(_Float16)a.x; r[1]=(_Float16)a.y; r[2]=(_Float16)a.z; r[3]=(_Float16)a.w;
        r[4]=(_Float16)c.x; r[5]=(_Float16)c.y; r[6]=(_Float16)c.z; r[7]=(_Float16)c.w;
        *(f16x8*)(hh + (size_t)node * 64 + seg * 8) = r;
    } else if (b < ZB + PHB + PWB) {                   // pack weights (16x16 frags)
        const int t2 = (b - ZB - PHB) * 256 + tid;
        if (t2 < 1024) {                               // msg_w1 [128,64]
            const int t = t2 >> 8, kk = (t2 >> 6) & 3, l = t2 & 63;
            f16x8 r;
#pragma unroll
            for (int j = 0; j < 8; ++j)
                r[j] = (_Float16)mw1[(kk * 32 + (l >> 4) * 8 + j) * 64 + t * 16 + (l & 15)];
            *(f16x8*)(mw1f + (size_t)t2 * 8) = r;
        } else if (t2 < 1536) {                        // msg_w2 [64,64]
            const int i = t2 - 1024;
            const int t = i >> 7, kk = (i >> 6) & 1, l = i & 63;
            f16x8 r;
#pragma unroll
            for (int j = 0; j < 8; ++j)
                r[j] = (_Float16)mw2[(kk * 32 + (l >> 4) * 8 + j) * 64 + t * 16 + (l & 15)];
            *(f16x8*)(mw2f + (size_t)i * 8) = r;
        } else if (t2 < 2560) {                        // upd_w1 [128,64]
            const int i = t2 - 1536;
            const int t = i >> 8, kk = (i >> 6) & 3, l = i & 63;
            f16x8 r;
#pragma unroll
            for (int j = 0; j < 8; ++j)
                r[j] = (_Float16)uw1[(kk * 32 + (l >> 4) * 8 + j) * 64 + t * 16 + (l & 15)];
            *(f16x8*)(uw1f + (size_t)i * 8) = r;
        } else if (t2 < 3072) {                        // upd_w2 [64,64]
            const int i = t2 - 2560;
            const int t = i >> 7, kk = (i >> 6) & 1, l = i & 63;
            f16x8 r;
#pragma unroll
            for (int j = 0; j < 8; ++j)
                r[j] = (_Float16)uw2[(kk * 32 + (l >> 4) * 8 + j) * 64 + t * 16 + (l & 15)];
            *(f16x8*)(uw2f + (size_t)i * 8) = r;
        } else if (t2 < 3328) {                        // pred_w [64,32]
            const int i = t2 - 3072;
            const int t = i >> 7, kk = (i >> 6) & 1, l = i & 63;
            f16x8 r;
#pragma unroll
            for (int j = 0; j < 8; ++j)
                r[j] = (_Float16)pw[(kk * 32 + (l >> 4) * 8 + j) * 32 + t * 16 + (l & 15)];
            *(f16x8*)(pwf + (size_t)i * 8) = r;
        }
    } else {                                           // sortA: LDS bucket hist
        const int blk = b - (ZB + PHB + PWB);
        for (int i = tid; i < NBKT; i += 256) lh[i] = 0;
        __syncthreads();
        const int e0 = blk * EPB;
#pragma unroll
        for (int k = 0; k < EPB / 256; ++k) {
            const int e = e0 + k * 256 + tid;
            if (e < NE) atomicAdd(&lh[ei[NE + e] >> 8], 1);
        }
        __syncthreads();
        for (int i = tid; i < NBKT; i += 256) cntm[blk * NBKT + i] = lh[i];
    }
}

// ===================== scancol: per-bucket column scan ====================
extern "C" __global__ void __launch_bounds__(512)
scancol_kernel(const int* __restrict__ cntm, int* __restrict__ offs,
               int* __restrict__ btot)
{
    __shared__ int s[512];
    const int tid = threadIdx.x, bkt = blockIdx.x;
    const int v = (tid < SB) ? cntm[tid * NBKT + bkt] : 0;
    s[tid] = v;
    __syncthreads();
    for (int off = 1; off < 512; off <<= 1) {
        int t = (tid >= off) ? s[tid - off] : 0;
        __syncthreads();
        s[tid] += t;
        __syncthreads();
    }
    if (tid < SB) offs[tid * NBKT + bkt] = s[tid] - v;   // exclusive in column
    if (tid == SB - 1) btot[bkt] = s[tid];
}

// ===================== scanb: bucket base prefix (1 block) ================
extern "C" __global__ void __launch_bounds__(512)
scanb_kernel(const int* __restrict__ btot, int* __restrict__ bbase)
{
    __shared__ int s[512];
    const int tid = threadIdx.x;
    const int v = (tid < NBKT) ? btot[tid] : 0;
    s[tid] = v;
    __syncthreads();
    for (int off = 1; off < 512; off <<= 1) {
        int t = (tid >= off) ? s[tid - off] : 0;
        __syncthreads();
        s[tid] += t;
        __syncthreads();
    }
    if (tid < NBKT) bbase[tid] = s[tid] - v;             // exclusive
    if (tid == NBKT - 1) bbase[NBKT] = s[tid];           // total
}

// ===================== sortC: scatter edges into bucket-grouped order =====
extern "C" __global__ void __launch_bounds__(256)
sortC_kernel(const int* __restrict__ ei, const int* __restrict__ offs,
             const int* __restrict__ bbase, int2* __restrict__ sd_tmp)
{
    __shared__ int lh[NBKT];
    __shared__ int lo[NBKT];
    const int tid = threadIdx.x, blk = blockIdx.x;
    for (int i = tid; i < NBKT; i += 256) {
        lh[i] = 0;
        lo[i] = bbase[i] + offs[blk * NBKT + i];
    }
    __syncthreads();
    const int e0 = blk * EPB;
#pragma unroll
    for (int k = 0; k < EPB / 256; ++k) {
        const int e = e0 + k * 256 + tid;
        if (e < NE) {
            const int s = ei[e], d = ei[NE + e];
            const int bkt = d >> 8;
            const int r = atomicAdd(&lh[bkt], 1);
            sd_tmp[lo[bkt] + r] = make_int2(s, d);
        }
    }
}

// ===================== sortD: within-bucket dst sort ======================
extern "C" __global__ void __launch_bounds__(256)
sortD_kernel(const int2* __restrict__ sd_tmp, const int* __restrict__ bbase,
             int2* __restrict__ sd2)
{
    __shared__ int h[256];
    __shared__ int s[256];
    __shared__ int dbase[256];
    const int tid = threadIdx.x, bkt = blockIdx.x;
    const int s0 = bbase[bkt], s1 = bbase[bkt + 1];
    const int n = s1 - s0;
    h[tid] = 0;
    __syncthreads();
    for (int k = tid; k < n; k += 256)
        atomicAdd(&h[sd_tmp[s0 + k].y & 255], 1);
    __syncthreads();
    const int v = h[tid];
    s[tid] = v;
    __syncthreads();
    for (int off = 1; off < 256; off <<= 1) {
        int t = (tid >= off) ? s[tid - off] : 0;
        __syncthreads();
        s[tid] += t;
        __syncthreads();
    }
    dbase[tid] = s[tid] - v;
    __syncthreads();
    h[tid] = 0;           // reuse as running rank
    __syncthreads();
    for (int k = tid; k < n; k += 256) {
        const int2 e = sd_tmp[s0 + k];
        const int dl = e.y & 255;
        const int r = atomicAdd(&h[dl], 1);
        sd2[s0 + dbase[dl] + r] = e;
    }
}

// ===================== fused edge MLP + register segmented aggregation ====
// Block = 8 waves (512 thr); wave owns 64 consecutive dst-sorted slots.
// LDS = 24KB weights + 8x2KB scratch = 40KB.
// launch_bounds(512,4): VGPR budget 128 -> compiles at ~60 VGPR, no spill.
// (r14's 3-deep prefetch and r12/r13 variants all regressed; this is the
// twice-verified 76.7us configuration.)
extern "C" __global__ void __launch_bounds__(512, 4)
edgeagg_kernel(const _Float16* __restrict__ hh,
               const int2* __restrict__ sd,
               const _Float16* __restrict__ w1f, const _Float16* __restrict__ w2f,
               const float* __restrict__ b1, const float* __restrict__ b2,
               float* __restrict__ aggr)
{
    __shared__ _Float16 sW1[4 * 4 * 64 * 8];   // 16 KB
    __shared__ _Float16 sW2[4 * 2 * 64 * 8];   // 8 KB
    __shared__ _Float16 sT[8][16 * 64];        // 16 KB (wave-private Y)

    const int tid = threadIdx.x;
    const int wave = tid >> 6, lane = tid & 63;
    const int m = lane & 15, g = lane >> 4;
    const int wslot = (blockIdx.x * 8 + wave) * 64;

    const int2 sdv = sd[wslot + lane];

    const int prevd = __shfl_up(sdv.y, 1, 64);
    const unsigned long long bmask = __ballot(lane == 0 || sdv.y != prevd);

    {   // stage W fragments (24 KB, block-shared, 512 threads)
        const uint4* g1 = (const uint4*)w1f; uint4* s1 = (uint4*)sW1;
#pragma unroll
        for (int i = 0; i < 2; ++i) s1[i * 512 + tid] = g1[i * 512 + tid];
        const uint4* g2 = (const uint4*)w2f; uint4* s2 = (uint4*)sW2;
        s2[tid] = g2[tid];
    }

    const float bb1[4] = { b1[m], b1[16 + m], b1[32 + m], b1[48 + m] };
    const float bb2[4] = { b2[m], b2[16 + m], b2[32 + m], b2[48 + m] };

    __syncthreads();   // the only block barrier

    _Float16* Y = sT[wave];

    float racc = 0.0f;
    int   rnode = __builtin_amdgcn_readlane(sdv.y, 0);
    int   firstRun = 1;

    f16x8 Abuf[2][4];
    {
        const int ns = __shfl(sdv.x, m, 64);
        const int nd = __shfl(sdv.y, m, 64);
        const _Float16* hd = hh + (size_t)nd * 64 + g * 8;
        const _Float16* hs = hh + (size_t)ns * 64 + g * 8;
        Abuf[0][0] = *(const f16x8*)(hd);
        Abuf[0][1] = *(const f16x8*)(hd + 32);
        Abuf[0][2] = *(const f16x8*)(hs);
        Abuf[0][3] = *(const f16x8*)(hs + 32);
    }

#pragma unroll
    for (int it = 0; it < 4; ++it) {
        const int cur = it & 1;
        if (it < 3) {
            const int ns = __shfl(sdv.x, (it + 1) * 16 + m, 64);
            const int nd = __shfl(sdv.y, (it + 1) * 16 + m, 64);
            const _Float16* hd = hh + (size_t)nd * 64 + g * 8;
            const _Float16* hs = hh + (size_t)ns * 64 + g * 8;
            Abuf[cur ^ 1][0] = *(const f16x8*)(hd);
            Abuf[cur ^ 1][1] = *(const f16x8*)(hd + 32);
            Abuf[cur ^ 1][2] = *(const f16x8*)(hs);
            Abuf[cur ^ 1][3] = *(const f16x8*)(hs + 32);
        }

        // ---- layer 1: 16 MFMAs
        f32x4 acc[4] = {};
#pragma unroll
        for (int t = 0; t < 4; ++t) {
#pragma unroll
            for (int kk = 0; kk < 4; ++kk) {
                const f16x8 b = *(const f16x8*)(sW1 + ((t * 4 + kk) * 64 + lane) * 8);
                acc[t] = __builtin_amdgcn_mfma_f32_16x16x32_f16(Abuf[cur][kk], b, acc[t], 0, 0, 0);
            }
        }

        // ---- bias+relu -> fp16 -> swizzled wave-private Y tile
#pragma unroll
        for (int t = 0; t < 4; ++t) {
#pragma unroll
            for (int r = 0; r < 4; ++r) {
                const float y = fmaxf(acc[t][r] + bb1[t], 0.0f);
                const int row = g * 4 + r, col = t * 16 + m;
                const int byteoff = row * 128 + ((2 * col) ^ ((row & 7) << 4));
                *(_Float16*)((char*)Y + byteoff) = (_Float16)y;
            }
        }
        asm volatile("s_waitcnt lgkmcnt(0)" ::: "memory");
        __builtin_amdgcn_sched_barrier(0);

        // ---- layer 2 A-frags from swizzled Y
        f16x8 a2[2];
#pragma unroll
        for (int kk = 0; kk < 2; ++kk) {
            const int c = kk * 4 + g;
            a2[kk] = *(const f16x8*)((char*)Y + m * 128 + ((c * 16) ^ ((m & 7) << 4)));
        }
        asm volatile("s_waitcnt lgkmcnt(0)" ::: "memory");
        __builtin_amdgcn_sched_barrier(0);

        // ---- layer 2: 8 MFMAs -> M in registers
        f32x4 acc2[4] = {};
#pragma unroll
        for (int kk = 0; kk < 2; ++kk) {
#pragma unroll
            for (int t = 0; t < 4; ++t) {
                const f16x8 b = *(const f16x8*)(sW2 + ((t * 2 + kk) * 64 + lane) * 8);
                acc2[t] = __builtin_amdgcn_mfma_f32_16x16x32_f16(a2[kk], b, acc2[t], 0, 0, 0);
            }
        }
#pragma unroll
        for (int t = 0; t < 4; ++t)
#pragma unroll
            for (int r = 0; r < 4; ++r) acc2[t][r] += bb2[t];

        // ---- register segmented reduction over dst runs in this tile
        const unsigned tm = (unsigned)((bmask >> (it * 16)) & 0xFFFFull) | 0x10000u;
        if (tm == 0x10000u) {
            // fast path: whole tile continues the current run
            float p0 = 0.f, p1 = 0.f, p2 = 0.f, p3 = 0.f;
#pragma unroll
            for (int r = 0; r < 4; ++r) {
                p0 += acc2[0][r]; p1 += acc2[1][r];
                p2 += acc2[2][r]; p3 += acc2[3][r];
            }
            p0 += __shfl_xor(p0, 16); p0 += __shfl_xor(p0, 32);
            p1 += __shfl_xor(p1, 16); p1 += __shfl_xor(p1, 32);
            p2 += __shfl_xor(p2, 16); p2 += __shfl_xor(p2, 32);
            p3 += __shfl_xor(p3, 16); p3 += __shfl_xor(p3, 32);
            racc += (g == 0) ? p0 : (g == 1) ? p1 : (g == 2) ? p2 : p3;
        } else {
            int a = 0;
            while (a < 16) {
                const int b = a + 1 + __builtin_ctz(tm >> (a + 1));   // segment [a,b)
                const int d = __builtin_amdgcn_readlane(sdv.y, it * 16 + a);
                if (d != rnode) {
                    float* ap = aggr + (size_t)rnode * 64 + lane;
                    if (firstRun) atomicAdd(ap, racc);
                    else          *ap = racc;
                    firstRun = 0; racc = 0.0f; rnode = d;
                }
                float p0 = 0.f, p1 = 0.f, p2 = 0.f, p3 = 0.f;
#pragma unroll
                for (int r = 0; r < 4; ++r) {
                    const int rowl = 4 * g + r;
                    const bool in = (rowl >= a) && (rowl < b);
                    p0 += in ? acc2[0][r] : 0.f;
                    p1 += in ? acc2[1][r] : 0.f;
                    p2 += in ? acc2[2][r] : 0.f;
                    p3 += in ? acc2[3][r] : 0.f;
                }
                p0 += __shfl_xor(p0, 16); p0 += __shfl_xor(p0, 32);
                p1 += __shfl_xor(p1, 16); p1 += __shfl_xor(p1, 32);
                p2 += __shfl_xor(p2, 16); p2 += __shfl_xor(p2, 32);
                p3 += __shfl_xor(p3, 16); p3 += __shfl_xor(p3, 32);
                racc += (g == 0) ? p0 : (g == 1) ? p1 : (g == 2) ? p2 : p3;
                a = b;
            }
        }
    }
    atomicAdd(aggr + (size_t)rnode * 64 + lane, racc);
}

// ===================== MFMA node kernel: h + fp32 aggr -> upd -> pred =====
extern "C" __global__ void __launch_bounds__(256)
node_mfma_kernel(const _Float16* __restrict__ hh, const float* __restrict__ aggr,
                 const _Float16* __restrict__ uw1f, const _Float16* __restrict__ uw2f,
                 const _Float16* __restrict__ pwf,
                 const float* __restrict__ b1, const float* __restrict__ b2,
                 const float* __restrict__ pb, float* __restrict__ out)
{
    __shared__ _Float16 sU1[4 * 4 * 64 * 8];   // 16 KB
    __shared__ _Float16 sU2[4 * 2 * 64 * 8];   // 8 KB
    __shared__ _Float16 sPW[2 * 2 * 64 * 8];   // 4 KB
    __shared__ _Float16 sT[4][16 * 64];        // 8 KB

    const int tid = threadIdx.x;
    {
        const uint4* g1 = (const uint4*)uw1f; uint4* s1 = (uint4*)sU1;
#pragma unroll
        for (int i = 0; i < 4; ++i) s1[i * 256 + tid] = g1[i * 256 + tid];
        const uint4* g2 = (const uint4*)uw2f; uint4* s2 = (uint4*)sU2;
#pragma unroll
        for (int i = 0; i < 2; ++i) s2[i * 256 + tid] = g2[i * 256 + tid];
        const uint4* g3 = (const uint4*)pwf;  uint4* s3 = (uint4*)sPW;
        s3[tid] = g3[tid];
    }
    __syncthreads();

    const int wave = tid >> 6, lane = tid & 63;
    const int m = lane & 15, g = lane >> 4;
    const int nb = (blockIdx.x * 4 + wave) * 16;
    const int v = nb + m;
    const int vl = (v < NN) ? v : (NN - 1);

    const _Float16* hv = hh + (size_t)vl * 64 + g * 8;
    const f16x8 a0 = *(const f16x8*)(hv);
    const f16x8 a1 = *(const f16x8*)(hv + 32);
    const float* av = aggr + (size_t)vl * 64 + g * 8;
    const float4 x0 = *(const float4*)(av),      x1 = *(const float4*)(av + 4);
    const float4 y0 = *(const float4*)(av + 32), y1 = *(const float4*)(av + 36);
    f16x8 a2, a3;
    a2[0]=(_Float16)x0.x; a2[1]=(_Float16)x0.y; a2[2]=(_Float16)x0.z; a2[3]=(_Float16)x0.w;
    a2[4]=(_Float16)x1.x; a2[5]=(_Float16)x1.y; a2[6]=(_Float16)x1.z; a2[7]=(_Float16)x1.w;
    a3[0]=(_Float16)y0.x; a3[1]=(_Float16)y0.y; a3[2]=(_Float16)y0.z; a3[3]=(_Float16)y0.w;
    a3[4]=(_Float16)y1.x; a3[5]=(_Float16)y1.y; a3[6]=(_Float16)y1.z; a3[7]=(_Float16)y1.w;

    // layer 1
    f32x4 acc[4] = {};
#pragma unroll
    for (int t = 0; t < 4; ++t) {
        acc[t] = __builtin_amdgcn_mfma_f32_16x16x32_f16(
            a0, *(const f16x8*)(sU1 + ((t * 4 + 0) * 64 + lane) * 8), acc[t], 0, 0, 0);
        acc[t] = __builtin_amdgcn_mfma_f32_16x16x32_f16(
            a1, *(const f16x8*)(sU1 + ((t * 4 + 1) * 64 + lane) * 8), acc[t], 0, 0, 0);
        acc[t] = __builtin_amdgcn_mfma_f32_16x16x32_f16(
            a2, *(const f16x8*)(sU1 + ((t * 4 + 2) * 64 + lane) * 8), acc[t], 0, 0, 0);
        acc[t] = __builtin_amdgcn_mfma_f32_16x16x32_f16(
            a3, *(const f16x8*)(sU1 + ((t * 4 + 3) * 64 + lane) * 8), acc[t], 0, 0, 0);
    }

    _Float16* Y = sT[wave];
#pragma unroll
    for (int t = 0; t < 4; ++t) {
        const float bb = b1[t * 16 + m];
#pragma unroll
        for (int r = 0; r < 4; ++r) {
            const float y = fmaxf(acc[t][r] + bb, 0.0f);
            const int row = g * 4 + r, col = t * 16 + m;
            const int byteoff = row * 128 + ((2 * col) ^ ((row & 7) << 4));
            *(_Float16*)((char*)Y + byteoff) = (_Float16)y;
        }
    }
    asm volatile("s_waitcnt lgkmcnt(0)" ::: "memory");
    __builtin_amdgcn_sched_barrier(0);

    f16x8 ay[2];
#pragma unroll
    for (int kk = 0; kk < 2; ++kk) {
        const int c = kk * 4 + g;
        ay[kk] = *(const f16x8*)((char*)Y + m * 128 + ((c * 16) ^ ((m & 7) << 4)));
    }
    asm volatile("s_waitcnt lgkmcnt(0)" ::: "memory");
    __builtin_amdgcn_sched_barrier(0);

    // layer 2
    f32x4 acc2[4] = {};
#pragma unroll
    for (int kk = 0; kk < 2; ++kk) {
#pragma unroll
        for (int t = 0; t < 4; ++t) {
            const f16x8 b = *(const f16x8*)(sU2 + ((t * 2 + kk) * 64 + lane) * 8);
            acc2[t] = __builtin_amdgcn_mfma_f32_16x16x32_f16(ay[kk], b, acc2[t], 0, 0, 0);
        }
    }

#pragma unroll
    for (int t = 0; t < 4; ++t) {
        const float bb = b2[t * 16 + m];
#pragma unroll
        for (int r = 0; r < 4; ++r) {
            const float u = acc2[t][r] + bb;
            const int row = g * 4 + r, col = t * 16 + m;
            const int byteoff = row * 128 + ((2 * col) ^ ((row & 7) << 4));
            *(_Float16*)((char*)Y + byteoff) = (_Float16)u;
        }
    }
    asm volatile("s_waitcnt lgkmcnt(0)" ::: "memory");
    __builtin_amdgcn_sched_barrier(0);

    f16x8 au[2];
#pragma unroll
    for (int kk = 0; kk < 2; ++kk) {
        const int c = kk * 4 + g;
        au[kk] = *(const f16x8*)((char*)Y + m * 128 + ((c * 16) ^ ((m & 7) << 4)));
    }
    asm volatile("s_waitcnt lgkmcnt(0)" ::: "memory");
    __builtin_amdgcn_sched_barrier(0);

    // pred head: 64 -> 32
    f32x4 acc3[2] = {};
#pragma unroll
    for (int kk = 0; kk < 2; ++kk) {
#pragma unroll
        for (int t = 0; t < 2; ++t) {
            const f16x8 b = *(const f16x8*)(sPW + ((t * 2 + kk) * 64 + lane) * 8);
            acc3[t] = __builtin_amdgcn_mfma_f32_16x16x32_f16(au[kk], b, acc3[t], 0, 0, 0);
        }
    }

    float* F = (float*)Y;
#pragma unroll
    for (int t = 0; t < 2; ++t) {
        const float bb = pb[t * 16 + m];
#pragma unroll
        for (int r = 0; r < 4; ++r) {
            const int row = g * 4 + r, col = t * 16 + m;
            const int byteoff = row * 128 + ((4 * col) ^ ((row & 7) << 4));
            *(float*)((char*)F + byteoff) = acc3[t][r] + bb;
        }
    }
    asm volatile("s_waitcnt lgkmcnt(0)" ::: "memory");
    __builtin_amdgcn_sched_barrier(0);

    const int row = lane >> 2, q = lane & 3;
    const float4 o0 = *(const float4*)((char*)F + row * 128 + ((q * 16)       ^ ((row & 7) << 4)));
    const float4 o1 = *(const float4*)((char*)F + row * 128 + (((q + 4) * 16) ^ ((row & 7) << 4)));
    if (nb + row < NN) {
        float4* op = (float4*)(out + (size_t)(nb + row) * 32);
        op[q]     = o0;
        op[q + 4] = o1;
    }
}

// ===================== fallback: atomic edge kernel + scalar node =========
extern "C" __global__ void __launch_bounds__(256)
edge_msg_kernel(const float* __restrict__ pos, const float* __restrict__ vel,
                const int* __restrict__ ei,
                const float* __restrict__ w1, const float* __restrict__ b1,
                const float* __restrict__ w2, const float* __restrict__ b2,
                float* __restrict__ aggr)
{
    const int e = blockIdx.x * 256 + threadIdx.x;
    if (e >= NE) return;
    const int ns = ei[e];
    const int nd = ei[NE + e];
    float y[64];
#pragma unroll
    for (int j = 0; j < 64; ++j) y[j] = b1[j];
    for (int part = 0; part < 4; ++part) {
        const int    node  = (part < 2) ? nd : ns;
        const float* basep = (part & 1) ? vel : pos;
        const float4* xp = reinterpret_cast<const float4*>(basep + (size_t)node * 32);
        const float*  wp = w1 + part * 32 * 64;
        for (int q = 0; q < 8; ++q) {
            const float4 xv = xp[q];
#pragma unroll
            for (int kk = 0; kk < 4; ++kk) {
                const float xs = (kk == 0) ? xv.x : (kk == 1) ? xv.y
                               : (kk == 2) ? xv.z : xv.w;
                const float* wr = wp + (q * 4 + kk) * 64;
#pragma unroll
                for (int j = 0; j < 64; ++j) y[j] = fmaf(xs, wr[j], y[j]);
            }
        }
    }
    float mm[64];
#pragma unroll
    for (int c = 0; c < 64; ++c) mm[c] = b2[c];
#pragma unroll
    for (int j = 0; j < 64; ++j) {
        const float yj = fmaxf(y[j], 0.0f);
        const float* wr = w2 + j * 64;
#pragma unroll
        for (int c = 0; c < 64; ++c) mm[c] = fmaf(yj, wr[c], mm[c]);
    }
    float* ap = aggr + (size_t)nd * 64;
#pragma unroll
    for (int c = 0; c < 64; ++c) atomicAdd(ap + c, mm[c]);
}

extern "C" __global__ void __launch_bounds__(256)
node_upd_kernel(const float* __restrict__ pos, const float* __restrict__ vel,
                const float* __restrict__ aggr,
                const float* __restrict__ w1, const float* __restrict__ b1,
                const float* __restrict__ w2, const float* __restrict__ b2,
                const float* __restrict__ pw, const float* __restrict__ pb,
                float* __restrict__ out)
{
    const int v = blockIdx.x * 256 + threadIdx.x;
    if (v >= NN) return;

    float y[64];
#pragma unroll
    for (int j = 0; j < 64; ++j) y[j] = b1[j];
    for (int part = 0; part < 4; ++part) {
        const float* basep = (part == 0) ? pos + (size_t)v * 32
                           : (part == 1) ? vel + (size_t)v * 32
                           : aggr + (size_t)v * 64 + (size_t)(part - 2) * 32;
        const float4* xp = reinterpret_cast<const float4*>(basep);
        const float*  wp = w1 + part * 32 * 64;
        for (int q = 0; q < 8; ++q) {
            const float4 xv = xp[q];
#pragma unroll
            for (int kk = 0; kk < 4; ++kk) {
                const float xs = (kk == 0) ? xv.x : (kk == 1) ? xv.y
                               : (kk == 2) ? xv.z : xv.w;
                const float* wr = wp + (q * 4 + kk) * 64;
#pragma unroll
                for (int j = 0; j < 64; ++j) y[j] = fmaf(xs, wr[j], y[j]);
            }
        }
    }

    float u[64];
#pragma unroll
    for (int c = 0; c < 64; ++c) u[c] = b2[c];
#pragma unroll
    for (int j = 0; j < 64; ++j) {
        const float yj = fmaxf(y[j], 0.0f);
        const float* wr = w2 + j * 64;
#pragma unroll
        for (int c = 0; c < 64; ++c) u[c] = fmaf(yj, wr[c], u[c]);
    }

    float o[32];
#pragma unroll
    for (int c = 0; c < 32; ++c) o[c] = pb[c];
#pragma unroll
    for (int j = 0; j < 64; ++j) {
        const float* wr = pw + j * 32;
#pragma unroll
        for (int c = 0; c < 32; ++c) o[c] = fmaf(u[j], wr[c], o[c]);
    }

    float4* op = reinterpret_cast<float4*>(out + (size_t)v * 32);
#pragma unroll
    for (int q = 0; q < 8; ++q)
        op[q] = make_float4(o[q * 4], o[q * 4 + 1], o[q * 4 + 2], o[q * 4 + 3]);
}

// ===================== launcher ===========================================
extern "C" void kernel_launch(void* const* d_in, const int* in_sizes, int n_in,
                              void* d_out, int out_size, void* d_ws, size_t ws_size,
                              hipStream_t stream)
{
    const float* pos = (const float*)d_in[0];
    const float* vel = (const float*)d_in[1];
    const int*   ei  = (const int*)d_in[2];
    const float* mw1 = (const float*)d_in[3];
    const float* mb1 = (const float*)d_in[4];
    const float* mw2 = (const float*)d_in[5];
    const float* mb2 = (const float*)d_in[6];
    const float* uw1 = (const float*)d_in[7];
    const float* ub1 = (const float*)d_in[8];
    const float* uw2 = (const float*)d_in[9];
    const float* ub2 = (const float*)d_in[10];
    const float* pw  = (const float*)d_in[11];
    const float* pb  = (const float*)d_in[12];
    float* out = (float*)d_out;

    // workspace layout (~66 MB total)
    char* ws = (char*)d_ws;
    size_t off = 0;
    float*    aggr   = (float*)(ws + off);    off += (size_t)NN * 64 * 4;     // 25.6 MB
    _Float16* hh     = (_Float16*)(ws + off); off += (size_t)NN * 64 * 2;     // 12.8 MB
    int2*     sd_tmp = (int2*)(ws + off);     off += (size_t)NE * 8;          // 12.8 MB
    int2*     sd2    = (int2*)(ws + off);     off += (size_t)NE * 8;          // 12.8 MB
    int*      cntm   = (int*)(ws + off);      off += (size_t)SB * NBKT * 4;   // 611 KB
    int*      offs   = (int*)(ws + off);      off += (size_t)SB * NBKT * 4;   // 611 KB
    int*      btot   = (int*)(ws + off);      off += 512 * 4;
    int*      bbase  = (int*)(ws + off);      off += 512 * 4;
    _Float16* mw1f   = (_Float16*)(ws + off); off += 1024 * 8 * 2;            // 16 KB
    _Float16* mw2f   = (_Float16*)(ws + off); off += 512 * 8 * 2;             // 8 KB
    _Float16* uw1f   = (_Float16*)(ws + off); off += 1024 * 8 * 2;            // 16 KB
    _Float16* uw2f   = (_Float16*)(ws + off); off += 512 * 8 * 2;             // 8 KB
    _Float16* pwf    = (_Float16*)(ws + off); off += 256 * 8 * 2;             // 4 KB
    const size_t need_full = off;

    if (ws_size >= need_full) {
        prep_kernel<<<ZB + PHB + PWB + SB, 256, 0, stream>>>(
            pos, vel, ei, mw1, mw2, uw1, uw2, pw,
            hh, mw1f, mw2f, uw1f, uw2f, pwf, aggr, cntm);
        scancol_kernel<<<NBKT, 512, 0, stream>>>(cntm, offs, btot);
        scanb_kernel<<<1, 512, 0, stream>>>(btot, bbase);
        sortC_kernel<<<SB, 256, 0, stream>>>(ei, offs, bbase, sd_tmp);
        sortD_kernel<<<NBKT, 256, 0, stream>>>(sd_tmp, bbase, sd2);
        edgeagg_kernel<<<NE / 512, 512, 0, stream>>>(
            hh, sd2, mw1f, mw2f, mb1, mb2, aggr);
        node_mfma_kernel<<<(NN + 63) / 64, 256, 0, stream>>>(
            hh, aggr, uw1f, uw2f, pwf, ub1, ub2, pb, out);
    } else {
        // fallback: atomic path (needs only 25.6 MB)
        float* aggr2 = (float*)d_ws;
        hipMemsetAsync(aggr2, 0, (size_t)NN * 64 * sizeof(float), stream);
        edge_msg_kernel<<<NE / 256, 256, 0, stream>>>(pos, vel, ei,
                                                      mw1, mb1, mw2, mb2, aggr2);
        node_upd_kernel<<<(NN + 255) / 256, 256, 0, stream>>>(
            pos, vel, aggr2, uw1, ub1, uw2, ub2, pw, pb, out);
    }
}